// Round 9
// baseline (319.548 us; speedup 1.0000x reference)
//
#include <hip/hip_runtime.h>
#include <hip/hip_bf16.h>

#define N_NODES 100000
#define N_HEDGES 20000
#define N_EDGES 800000
#define HSEG (2 * N_HEDGES)            // 40000 hedge segments (t,h)
#define NSEG (2 * N_NODES)             // 200000 node segments (t,n)
#define MSEG (HSEG + NSEG)             // 240000 segments

// Two-level LDS bucket sort geometry:
#define EPB 4096                        // edges per pass-A/C block
#define NBLK_A ((N_EDGES + EPB - 1) / EPB)  // 196
#define NHB 313                         // hedge buckets: 128 segs each
#define NBUCK 704                       // + 391 node buckets: 512 segs each
#define TOTB (NBUCK * NBLK_A)           // 137,984 (bucket-major counts)
#define SCANB ((TOTB + 2047) / 2048)    // 68
#define RKCAP 8192                      // max entries/bucket (mean ~2.3K)

#define CAST_BLOCKS (N_NODES * 64 / 8 / 256)   // 3125
#define PACK_BLOCKS 16

#define MIX_PK  (4 * 4 * 64 * 8)        // 8192 packed bf16 fused-mix weights
#define GRU_PK  (2 * 2 * 12 * 64 * 8)   // 24576 for k_gru

typedef __hip_bfloat16 bf16;
typedef __attribute__((ext_vector_type(8))) short bf16x8;
typedef __attribute__((ext_vector_type(4))) float f32x4;

__device__ __forceinline__ bf16 f2b(float v) { return __float2bfloat16(v); }
__device__ __forceinline__ short f2s(float v) {
    bf16 b = __float2bfloat16(v);
    return *reinterpret_cast<short*>(&b);
}
__device__ __forceinline__ uint pk2(float a, float b) {
    return (uint)(unsigned short)f2s(a) | ((uint)(unsigned short)f2s(b) << 16);
}
__device__ __forceinline__ bf16x8 pack8(float4 a, float4 b) {
    bf16x8 r = {f2s(a.x), f2s(a.y), f2s(a.z), f2s(a.w),
                f2s(b.x), f2s(b.y), f2s(b.z), f2s(b.w)};
    return r;
}
__device__ __forceinline__ float fast_sigmoid(float x) {
    return __builtin_amdgcn_rcpf(1.f + __expf(-x));
}
__device__ __forceinline__ float fast_tanh(float x) {
    return 1.f - 2.f * __builtin_amdgcn_rcpf(1.f + __expf(2.f * x));
}

// ---------------------------------------------------------------------------
// FRONT kernel, three roles by blockIdx (unchanged — passed rounds 7/8).
// ---------------------------------------------------------------------------
__global__ __launch_bounds__(256) void k_front(
    const int* __restrict__ node_idx, const int* __restrict__ hedge_idx,
    const int* __restrict__ attr, uint* __restrict__ rk12,
    int* __restrict__ bcnt,
    const float* __restrict__ x, bf16* __restrict__ xb,
    const float* __restrict__ Wc, const float* __restrict__ Wm,
    const float* __restrict__ bc_g, const float* __restrict__ bm,
    const float* __restrict__ Wih, const float* __restrict__ Whh,
    bf16* __restrict__ gru_pk, bf16* __restrict__ mixf_pk,
    float* __restrict__ bfused) {
    __shared__ int bc[NBUCK];
    int b = blockIdx.x;
    int tid = threadIdx.x;
    if (b < NBLK_A) {
        for (int i = tid; i < NBUCK; i += 256) bc[i] = 0;
        __syncthreads();
        int e0 = b * EPB;
        for (int it = 0; it < EPB / 256; ++it) {
            int e = e0 + it * 256 + tid;
            if (e < N_EDGES) {
                int t = attr[e];
                int s1 = t * N_HEDGES + hedge_idx[e];
                int s2 = HSEG + t * N_NODES + node_idx[e];
                int b1 = s1 >> 7;
                int b2 = NHB + ((s2 - HSEG) >> 9);
                int r1 = atomicAdd(&bc[b1], 1);
                int r2 = atomicAdd(&bc[b2], 1);
                rk12[e] = (uint)(r1 & 0xFFFF) | ((uint)r2 << 16);
            }
        }
        __syncthreads();
        for (int i = tid; i < NBUCK; i += 256) bcnt[i * NBLK_A + b] = bc[i];
    } else if (b < NBLK_A + CAST_BLOCKS) {
        size_t i = ((size_t)(b - NBLK_A) * 256 + tid) * 8;
        const float* xp = x + i;
        float4 a = *(const float4*)xp;
        float4 bb = *(const float4*)(xp + 4);
        *(bf16x8*)(xb + i) = pack8(a, bb);
    } else {
        int idx = (b - NBLK_A - CAST_BLOCKS) * 256 + tid;
        int stride = PACK_BLOCKS * 256;
        for (int i = idx; i < GRU_PK; i += stride) {
            int j = i & 7;
            int r = i >> 3;
            int ln = r & 63;
            int r2i = r >> 6;
            int ct = r2i % 12;
            int r3 = r2i / 12;
            int kt = r3 & 1;
            int mat = r3 >> 1;
            int k = kt * 32 + ((ln >> 4) << 3) + j;
            int n = ct * 16 + (ln & 15);
            float v = mat == 0 ? Wih[k * 192 + n] : Whh[k * 192 + n];
            gru_pk[i] = f2b(v);
        }
        for (int i = idx; i < MIX_PK; i += stride) {
            int j = i & 7, ln = (i >> 3) & 63, r2i = i >> 9;
            int ct = r2i & 3, kt = r2i >> 2;
            int k = kt * 32 + ((ln >> 4) << 3) + j;   // 0..127 (concat dim)
            int n = ct * 16 + (ln & 15);
            int t = k >> 6, kk = k & 63;
            float s = 0.f;
            for (int q = 0; q < 64; ++q)
                s += Wc[((size_t)t * 64 + kk) * 64 + q] * Wm[(size_t)(t * 64 + q) * 64 + n];
            mixf_pk[i] = f2b(s);
        }
        for (int i = idx; i < 64; i += stride) {
            float s = bm[i];
            for (int q = 0; q < 64; ++q)
                s += bc_g[q] * Wm[(size_t)q * 64 + i] + bc_g[64 + q] * Wm[(size_t)(64 + q) * 64 + i];
            bfused[i] = s;
        }
    }
}

// ---------------------------------------------------------------------------
// Scan 1/3 over bcnt, IN-PLACE safe (block reads its range before writing).
// ---------------------------------------------------------------------------
__global__ __launch_bounds__(256) void k_scan1(const int* __restrict__ cnt,
                                               int* __restrict__ off,
                                               int* __restrict__ bsum) {
    __shared__ int s[256];
    int base = blockIdx.x * 2048 + threadIdx.x * 8;
    int v[8];
    int tsum = 0;
#pragma unroll
    for (int j = 0; j < 8; ++j) {
        int g = base + j;
        v[j] = (g < TOTB) ? cnt[g] : 0;
        tsum += v[j];
    }
    s[threadIdx.x] = tsum;
    __syncthreads();
    for (int o = 1; o < 256; o <<= 1) {
        int t = (threadIdx.x >= o) ? s[threadIdx.x - o] : 0;
        __syncthreads();
        s[threadIdx.x] += t;
        __syncthreads();
    }
    int run = s[threadIdx.x] - tsum;
#pragma unroll
    for (int j = 0; j < 8; ++j) {
        int g = base + j;
        if (g < TOTB) off[g] = run;
        run += v[j];
    }
    if (threadIdx.x == 255) bsum[blockIdx.x] = s[255];
}

__global__ __launch_bounds__(1024) void k_scan2(int* __restrict__ bsum) {
    __shared__ int s[1024];
    int tid = threadIdx.x;
    int v = (tid < SCANB) ? bsum[tid] : 0;
    s[tid] = v;
    __syncthreads();
    for (int o = 1; o < 1024; o <<= 1) {
        int t = (tid >= o) ? s[tid - o] : 0;
        __syncthreads();
        s[tid] += t;
        __syncthreads();
    }
    if (tid < SCANB) bsum[tid] = s[tid] - v;
}

__global__ __launch_bounds__(256) void k_scan3(int* __restrict__ off,
                                               const int* __restrict__ bsum) {
    int base = blockIdx.x * 2048 + threadIdx.x * 8;
    int add = bsum[blockIdx.x];
#pragma unroll
    for (int j = 0; j < 8; ++j) {
        int g = base + j;
        if (g < TOTB) off[g] += add;
    }
    if (blockIdx.x == 0 && threadIdx.x == 0) off[TOTB] = 2 * N_EDGES;  // sentinel
}

// ---------------------------------------------------------------------------
// Bucket-sort pass C: ATOMIC-FREE scatter into bucket-major pairs array.
// ---------------------------------------------------------------------------
__global__ __launch_bounds__(256) void k_bscatter(const int* __restrict__ node_idx,
                                                  const int* __restrict__ hedge_idx,
                                                  const int* __restrict__ attr,
                                                  const uint* __restrict__ rk12,
                                                  const int* __restrict__ bbase,
                                                  int2* __restrict__ pairs) {
    int b = blockIdx.x, tid = threadIdx.x;
    int e0 = b * EPB;
    for (int it = 0; it < EPB / 256; ++it) {
        int e = e0 + it * 256 + tid;
        if (e < N_EDGES) {
            int t = attr[e], n = node_idx[e], h = hedge_idx[e];
            int s1 = t * N_HEDGES + h;
            int s2 = HSEG + t * N_NODES + n;
            int b1 = s1 >> 7;
            int b2 = NHB + ((s2 - HSEG) >> 9);
            uint rk = rk12[e];
            int p1 = bbase[b1 * NBLK_A + b] + (int)(rk & 0xFFFF);
            int p2 = bbase[b2 * NBLK_A + b] + (int)(rk >> 16);
            pairs[p1] = make_int2(s1, n);
            pairs[p2] = make_int2(s2, t * N_HEDGES + h);
        }
    }
}

// ---------------------------------------------------------------------------
// Bucket-sort pass D: one block per bucket -> dense CSR off[] + sortedAll.
// ---------------------------------------------------------------------------
__global__ __launch_bounds__(256) void k_bfinal(const int* __restrict__ bbase,
                                                const int2* __restrict__ pairs,
                                                int* __restrict__ off,
                                                int* __restrict__ sortedAll) {
    __shared__ int scnt[512];
    __shared__ int exs[512];
    __shared__ int ssum[256];
    __shared__ unsigned short rk[RKCAP];
    int bucket = blockIdx.x, tid = threadIdx.x;
    int seg_first, nseg;
    if (bucket < NHB) {
        seg_first = bucket << 7;
        nseg = min(128, HSEG - seg_first);
    } else {
        int bi = bucket - NHB;
        seg_first = HSEG + (bi << 9);
        nseg = min(512, MSEG - seg_first);
    }
    int bstart = bbase[bucket * NBLK_A];
    int bend = bbase[(bucket + 1) * NBLK_A];   // sentinel covers last bucket
    for (int i = tid; i < 512; i += 256) scnt[i] = 0;
    __syncthreads();
    for (int i = bstart + tid; i < bend; i += 256) {
        int li = i - bstart;
        int key = pairs[i].x;
        int r = atomicAdd(&scnt[key - seg_first], 1);
        if (li < RKCAP) rk[li] = (unsigned short)r;
    }
    __syncthreads();
    int a0 = (2 * tid < nseg) ? scnt[2 * tid] : 0;
    int a1 = (2 * tid + 1 < nseg) ? scnt[2 * tid + 1] : 0;
    ssum[tid] = a0 + a1;
    __syncthreads();
    for (int o = 1; o < 256; o <<= 1) {
        int t = (tid >= o) ? ssum[tid - o] : 0;
        __syncthreads();
        ssum[tid] += t;
        __syncthreads();
    }
    int pb = ssum[tid] - (a0 + a1);
    exs[2 * tid] = pb;
    exs[2 * tid + 1] = pb + a0;
    if (2 * tid < nseg) off[seg_first + 2 * tid] = bstart + pb;
    if (2 * tid + 1 < nseg) off[seg_first + 2 * tid + 1] = bstart + pb + a0;
    if (bucket == NBUCK - 1 && tid == 0) off[MSEG] = 2 * N_EDGES;
    __syncthreads();
    for (int i = bstart + tid; i < bend; i += 256) {
        int li = i - bstart;
        if (li < RKCAP) {
            int2 pr = pairs[i];
            int pos = bstart + exs[pr.x - seg_first] + (int)rk[li];
            sortedAll[pos] = pr.y;
        }
    }
}

// ---------------------------------------------------------------------------
// One contiguous run: 2-deep pipelined gather (8-lane half-group, uint4).
// NO cross-lane combine here (caller shfl_xor(8)'s the final value).
// ---------------------------------------------------------------------------
__device__ __forceinline__ void run_gather(const int* __restrict__ sortedAll,
                                           const bf16* __restrict__ rows,
                                           int myb, int mye, int i0, int cb,
                                           float acc[8]) {
#pragma unroll
    for (int j = 0; j < 8; ++j) acc[j] = 0.f;
    int i = myb + i0;
    for (; i + 2 < mye; i += 4) {
        int idx0 = sortedAll[i];
        int idx1 = sortedAll[i + 2];
        uint4 v0 = *(const uint4*)(rows + (size_t)idx0 * 64 + cb);
        uint4 v1 = *(const uint4*)(rows + (size_t)idx1 * 64 + cb);
        acc[0] += __uint_as_float(v0.x << 16);
        acc[1] += __uint_as_float(v0.x & 0xffff0000u);
        acc[2] += __uint_as_float(v0.y << 16);
        acc[3] += __uint_as_float(v0.y & 0xffff0000u);
        acc[4] += __uint_as_float(v0.z << 16);
        acc[5] += __uint_as_float(v0.z & 0xffff0000u);
        acc[6] += __uint_as_float(v0.w << 16);
        acc[7] += __uint_as_float(v0.w & 0xffff0000u);
        acc[0] += __uint_as_float(v1.x << 16);
        acc[1] += __uint_as_float(v1.x & 0xffff0000u);
        acc[2] += __uint_as_float(v1.y << 16);
        acc[3] += __uint_as_float(v1.y & 0xffff0000u);
        acc[4] += __uint_as_float(v1.z << 16);
        acc[5] += __uint_as_float(v1.z & 0xffff0000u);
        acc[6] += __uint_as_float(v1.w << 16);
        acc[7] += __uint_as_float(v1.w & 0xffff0000u);
    }
    if (i < mye) {
        int idx = sortedAll[i];
        uint4 v = *(const uint4*)(rows + (size_t)idx * 64 + cb);
        acc[0] += __uint_as_float(v.x << 16);
        acc[1] += __uint_as_float(v.x & 0xffff0000u);
        acc[2] += __uint_as_float(v.y << 16);
        acc[3] += __uint_as_float(v.y & 0xffff0000u);
        acc[4] += __uint_as_float(v.z << 16);
        acc[5] += __uint_as_float(v.z & 0xffff0000u);
        acc[6] += __uint_as_float(v.w << 16);
        acc[7] += __uint_as_float(v.w & 0xffff0000u);
    }
}

// ---------------------------------------------------------------------------
// FUSED hedge gather + Wf GEMM: eg[t][h] = (Binv * sum xb rows) @ Wf_t.
// Mix algebra pushed to the 40K hedge rows (vs 200K node rows): each block's
// 16 segments form one 16x64 tile (20000%16==0 -> t-uniform). Gather ->
// XOR-swizzled LDS tile -> one barrier -> each wave MFMAs its 16-col slice
// with the 8KB Wf_t LDS slice -> D-layout scalar stores to eg16.
// ---------------------------------------------------------------------------
__global__ __launch_bounds__(256) void k_ef2w(const int* __restrict__ off,
                                              const int* __restrict__ sortedAll,
                                              const bf16* __restrict__ xb,
                                              const bf16* __restrict__ mixf_pk,
                                              bf16* __restrict__ eg16) {
    __shared__ __align__(16) bf16 Wl[2 * 4 * 64 * 8];  // 8 KB: this-t Wf slice
    __shared__ __align__(16) bf16 tile[16 * 64];       // 2 KB
    int seg0b = blockIdx.x * 16;
    int t = (seg0b >= N_HEDGES) ? 1 : 0;
    {
        const bf16x8* src = (const bf16x8*)(mixf_pk + t * 4096);
        bf16x8* dst = (bf16x8*)Wl;
        for (int i = threadIdx.x; i < 4096 / 8; i += 256) dst[i] = src[i];
    }
    int wid = threadIdx.x >> 6, lane = threadIdx.x & 63;
    int q = lane >> 4, l16 = lane & 15;

    // gather this wave's 4 segments (rows wid*4+q of the tile)
    int seg0 = seg0b + wid * 4;
    int ov = 0;
    if (lane < 5) ov = off[seg0 + lane];
    int myb = __shfl(ov, q);
    int mye = __shfl(ov, q + 1);
    float acc[8];
    run_gather(sortedAll, xb, myb, mye, l16 >> 3, (l16 & 7) * 8, acc);
#pragma unroll
    for (int j = 0; j < 8; ++j) acc[j] += __shfl_xor(acc[j], 8);
    float scale = (mye > myb) ? 1.0f / (float)(mye - myb) : 0.f;
    int r = wid * 4 + q;
    if (l16 < 8) {
        int cs = l16 ^ (r & 7);                    // chunk-XOR swizzle
        uint4 w;
        w.x = pk2(acc[0] * scale, acc[1] * scale);
        w.y = pk2(acc[2] * scale, acc[3] * scale);
        w.z = pk2(acc[4] * scale, acc[5] * scale);
        w.w = pk2(acc[6] * scale, acc[7] * scale);
        *(uint4*)&tile[r * 64 + cs * 8] = w;
    }
    __syncthreads();

    bf16x8 a0 = *(const bf16x8*)&tile[l16 * 64 + (q ^ (l16 & 7)) * 8];
    bf16x8 a1 = *(const bf16x8*)&tile[l16 * 64 + ((q + 4) ^ (l16 & 7)) * 8];
    const f32x4 zero = {0.f, 0.f, 0.f, 0.f};
#define LDW(ktl) (*(const bf16x8*)&Wl[(((ktl)*4 + wid) * 64 + lane) * 8])
    f32x4 d = __builtin_amdgcn_mfma_f32_16x16x32_bf16(a0, LDW(0), zero, 0, 0, 0);
    d = __builtin_amdgcn_mfma_f32_16x16x32_bf16(a1, LDW(1), d, 0, 0, 0);
#undef LDW
#pragma unroll
    for (int rg = 0; rg < 4; ++rg)
        eg16[(size_t)(seg0b + q * 4 + rg) * 64 + wid * 16 + l16] = f2b(d[rg]);
}

// ---------------------------------------------------------------------------
// Node aggregation, BOTH types fused: quarter owns node n; gathers its t=0
// and t=1 runs from eg16 (already Wf-weighted), h[n] = relu(a0*Dinv0 +
// a1*Dinv1 + bfused) -> hbuf16. agg16 round-trip (25.6MB w + 25.6MB r) gone.
// ---------------------------------------------------------------------------
__global__ __launch_bounds__(256) void k_no2h(const int* __restrict__ off,
                                              const int* __restrict__ sortedAll,
                                              const bf16* __restrict__ eg16,
                                              const float* __restrict__ bfused,
                                              bf16* __restrict__ hbuf16) {
    int wid = threadIdx.x >> 6, lane = threadIdx.x & 63;
    int n0 = (blockIdx.x * 4 + wid) * 4;
    if (n0 >= N_NODES) return;
    int q = lane >> 4, l16 = lane & 15;
    int cb = (l16 & 7) * 8, i0 = l16 >> 3;
    int ov = 0;
    if (lane < 5) ov = off[HSEG + n0 + lane];
    else if (lane >= 8 && lane < 13) ov = off[HSEG + N_NODES + n0 + (lane - 8)];
    int b0 = __shfl(ov, q), e0 = __shfl(ov, q + 1);
    int b1 = __shfl(ov, 8 + q), e1 = __shfl(ov, 9 + q);
    float a0[8], a1[8];
    run_gather(sortedAll, eg16, b0, e0, i0, cb, a0);
    run_gather(sortedAll, eg16, b1, e1, i0, cb, a1);
    float s0 = (e0 > b0) ? 1.0f / (float)(e0 - b0) : 0.f;
    float s1 = (e1 > b1) ? 1.0f / (float)(e1 - b1) : 0.f;
    float v[8];
#pragma unroll
    for (int j = 0; j < 8; ++j) {
        v[j] = a0[j] * s0 + a1[j] * s1;
        v[j] += __shfl_xor(v[j], 8);
    }
    if (l16 < 8) {
#pragma unroll
        for (int j = 0; j < 8; ++j) v[j] = fmaxf(v[j] + bfused[cb + j], 0.f);
        uint4 w;
        w.x = pk2(v[0], v[1]);
        w.y = pk2(v[2], v[3]);
        w.z = pk2(v[4], v[5]);
        w.w = pk2(v[6], v[7]);
        *(uint4*)(hbuf16 + (size_t)(n0 + q) * 64 + cb) = w;
    }
}

// ---------------------------------------------------------------------------
// PURE GRU (mix phase moved upstream). 512 threads, LDS 48KB -> 3 blocks/CU
// = 24 waves/CU (3x round-7's occupancy). Gate fusion r/z (4-MFMA chains),
// biases in C-init, fast sigmoid/tanh.
// ---------------------------------------------------------------------------
#define GRU_TILES (N_NODES / 16)
__global__ __launch_bounds__(512) void k_gru(const bf16* __restrict__ gru_pk,
                                             const bf16* __restrict__ hbuf16,
                                             const float* __restrict__ h_prev,
                                             const float* __restrict__ bih_g,
                                             const float* __restrict__ bhh_g,
                                             const float* __restrict__ Wro_g,
                                             const float* __restrict__ bro_g,
                                             float* __restrict__ out_h,
                                             float* __restrict__ out_o) {
    __shared__ __align__(16) bf16 Wpk[GRU_PK];      // 48 KB
    {
        const bf16x8* src = (const bf16x8*)gru_pk;
        bf16x8* dst = (bf16x8*)Wpk;
        for (int i = threadIdx.x; i < GRU_PK / 8; i += 512) dst[i] = src[i];
    }
    __syncthreads();

    int wid = threadIdx.x >> 6, lane = threadIdx.x & 63;
    int quad = lane >> 4, l16 = lane & 15;

    float br_c[4], bz_c[4], bin_c[4], bhn_c[4], wv[4][3];
#pragma unroll
    for (int cc = 0; cc < 4; ++cc) {
        int col = cc * 16 + l16;
        br_c[cc] = bih_g[col] + bhh_g[col];
        bz_c[cc] = bih_g[64 + col] + bhh_g[64 + col];
        bin_c[cc] = bih_g[128 + col];
        bhn_c[cc] = bhh_g[128 + col];
        wv[cc][0] = Wro_g[col * 64 + 0];
        wv[cc][1] = Wro_g[col * 64 + 1];
        wv[cc][2] = Wro_g[col * 64 + 2];
    }
    float bro0 = bro_g[0], bro1 = bro_g[1], bro2 = bro_g[2];

    int wave = blockIdx.x * 8 + wid;
    int n_waves = gridDim.x * 8;

    for (int tile = wave; tile < GRU_TILES; tile += n_waves) {
        int row0 = tile * 16;
        int arow = row0 + l16;
        const bf16* ha_p = hbuf16 + (size_t)arow * 64 + quad * 8;
        bf16x8 ha0 = *(const bf16x8*)ha_p;
        bf16x8 ha1 = *(const bf16x8*)(ha_p + 32);
        const float* pp = h_prev + (size_t)arow * 64 + quad * 8;
        bf16x8 pa0 = pack8(*(const float4*)pp, *(const float4*)(pp + 4));
        bf16x8 pa1 = pack8(*(const float4*)(pp + 32), *(const float4*)(pp + 36));

        float p[4][3];
#pragma unroll
        for (int rg = 0; rg < 4; ++rg) p[rg][0] = p[rg][1] = p[rg][2] = 0.f;

#pragma unroll
        for (int cc = 0; cc < 4; ++cc) {
#define LDB(mat, kt, ct) (*(const bf16x8*)&Wpk[((((mat)*2 + (kt)) * 12 + (ct)) * 64 + lane) * 8])
            f32x4 rs = {br_c[cc], br_c[cc], br_c[cc], br_c[cc]};
            f32x4 zs = {bz_c[cc], bz_c[cc], bz_c[cc], bz_c[cc]};
            f32x4 gin = {bin_c[cc], bin_c[cc], bin_c[cc], bin_c[cc]};
            f32x4 ghn = {bhn_c[cc], bhn_c[cc], bhn_c[cc], bhn_c[cc]};
            rs = __builtin_amdgcn_mfma_f32_16x16x32_bf16(ha0, LDB(0, 0, cc), rs, 0, 0, 0);
            rs = __builtin_amdgcn_mfma_f32_16x16x32_bf16(ha1, LDB(0, 1, cc), rs, 0, 0, 0);
            rs = __builtin_amdgcn_mfma_f32_16x16x32_bf16(pa0, LDB(1, 0, cc), rs, 0, 0, 0);
            rs = __builtin_amdgcn_mfma_f32_16x16x32_bf16(pa1, LDB(1, 1, cc), rs, 0, 0, 0);
            zs = __builtin_amdgcn_mfma_f32_16x16x32_bf16(ha0, LDB(0, 0, cc + 4), zs, 0, 0, 0);
            zs = __builtin_amdgcn_mfma_f32_16x16x32_bf16(ha1, LDB(0, 1, cc + 4), zs, 0, 0, 0);
            zs = __builtin_amdgcn_mfma_f32_16x16x32_bf16(pa0, LDB(1, 0, cc + 4), zs, 0, 0, 0);
            zs = __builtin_amdgcn_mfma_f32_16x16x32_bf16(pa1, LDB(1, 1, cc + 4), zs, 0, 0, 0);
            gin = __builtin_amdgcn_mfma_f32_16x16x32_bf16(ha0, LDB(0, 0, cc + 8), gin, 0, 0, 0);
            gin = __builtin_amdgcn_mfma_f32_16x16x32_bf16(ha1, LDB(0, 1, cc + 8), gin, 0, 0, 0);
            ghn = __builtin_amdgcn_mfma_f32_16x16x32_bf16(pa0, LDB(1, 0, cc + 8), ghn, 0, 0, 0);
            ghn = __builtin_amdgcn_mfma_f32_16x16x32_bf16(pa1, LDB(1, 1, cc + 8), ghn, 0, 0, 0);
#undef LDB
#pragma unroll
            for (int rg = 0; rg < 4; ++rg) {
                int row = row0 + quad * 4 + rg;
                float pv = h_prev[(size_t)row * 64 + cc * 16 + l16];
                float rr = fast_sigmoid(rs[rg]);
                float zz = fast_sigmoid(zs[rg]);
                float nn = fast_tanh(gin[rg] + rr * ghn[rg]);
                float hn = (1.f - zz) * nn + zz * pv;
                out_h[(size_t)row * 64 + cc * 16 + l16] = hn;
                p[rg][0] += hn * wv[cc][0];
                p[rg][1] += hn * wv[cc][1];
                p[rg][2] += hn * wv[cc][2];
            }
        }
#pragma unroll
        for (int rg = 0; rg < 4; ++rg) {
#pragma unroll
            for (int m = 1; m < 16; m <<= 1) {
                p[rg][0] += __shfl_xor(p[rg][0], m);
                p[rg][1] += __shfl_xor(p[rg][1], m);
                p[rg][2] += __shfl_xor(p[rg][2], m);
            }
        }
        if (l16 == 0) {
#pragma unroll
            for (int rg = 0; rg < 4; ++rg) {
                int row = row0 + quad * 4 + rg;
                out_o[(size_t)row * 3 + 0] = p[rg][0] + bro0;
                out_o[(size_t)row * 3 + 1] = p[rg][1] + bro1;
                out_o[(size_t)row * 3 + 2] = p[rg][2] + bro2;
            }
        }
    }
}

extern "C" void kernel_launch(void* const* d_in, const int* in_sizes, int n_in,
                              void* d_out, int out_size, void* d_ws, size_t ws_size,
                              hipStream_t stream) {
    const float* x        = (const float*)d_in[0];
    const float* h_prev   = (const float*)d_in[1];
    const int* node_idx   = (const int*)d_in[2];
    const int* hedge_idx  = (const int*)d_in[3];
    const int* edge_attr  = (const int*)d_in[4];
    const float* W_conv   = (const float*)d_in[5];
    const float* b_conv   = (const float*)d_in[6];
    const float* W_mix    = (const float*)d_in[7];
    const float* b_mix    = (const float*)d_in[8];
    const float* W_ih     = (const float*)d_in[9];
    const float* W_hh     = (const float*)d_in[10];
    const float* b_ih     = (const float*)d_in[11];
    const float* b_hh     = (const float*)d_in[12];
    const float* W_ro     = (const float*)d_in[13];
    const float* b_ro     = (const float*)d_in[14];

    char* p = (char*)d_ws;
    auto alloc = [&](size_t bytes) {
        char* r = p;
        p += (bytes + 63) & ~(size_t)63;
        return r;
    };
    // Region A (25.6MB): bucket-sort scratch {pairs 12.8MB, rk12 3.2MB,
    // bcnt 0.55MB, bsum 4KB} — all dead after k_bfinal — overlaid by
    // hbuf16 (12.8MB, first written in k_no2h).
    char* regA     = alloc((size_t)2 * N_NODES * 64 * 2);   // 25.6 MB
    int2* pairs    = (int2*)regA;
    uint* rk12     = (uint*)(pairs + 2 * N_EDGES);
    int* bcnt      = (int*)(rk12 + N_EDGES);
    int* bsum      = bcnt + TOTB + 1;
    bf16* hbuf16   = (bf16*)regA;
    int* off       = (int*)alloc((size_t)(MSEG + 1) * 4);   // live CSR ptrs
    int* sortedAll = (int*)alloc((size_t)2 * N_EDGES * 4);
    bf16* xb       = (bf16*)alloc((size_t)N_NODES * 64 * 2);
    bf16* eg16     = (bf16*)alloc((size_t)HSEG * 64 * 2);
    bf16* gru_pk   = (bf16*)alloc((size_t)GRU_PK * 2);
    bf16* mixf_pk  = (bf16*)alloc((size_t)MIX_PK * 2);
    float* bfused  = (float*)alloc(64 * 4);

    float* out_h = (float*)d_out;
    float* out_o = out_h + (size_t)N_NODES * 64;

    k_front<<<NBLK_A + CAST_BLOCKS + PACK_BLOCKS, 256, 0, stream>>>(
        node_idx, hedge_idx, edge_attr, rk12, bcnt, x, xb,
        W_conv, W_mix, b_conv, b_mix, W_ih, W_hh, gru_pk, mixf_pk, bfused);
    k_scan1<<<SCANB, 256, 0, stream>>>(bcnt, bcnt, bsum);   // in-place
    k_scan2<<<1, 1024, 0, stream>>>(bsum);
    k_scan3<<<SCANB, 256, 0, stream>>>(bcnt, bsum);
    k_bscatter<<<NBLK_A, 256, 0, stream>>>(node_idx, hedge_idx, edge_attr,
                                           rk12, bcnt, pairs);
    k_bfinal<<<NBUCK, 256, 0, stream>>>(bcnt, pairs, off, sortedAll);
    k_ef2w<<<HSEG / 16, 256, 0, stream>>>(off, sortedAll, xb, mixf_pk, eg16);
    k_no2h<<<N_NODES / 16, 256, 0, stream>>>(off, sortedAll, eg16, bfused, hbuf16);
    k_gru<<<(GRU_TILES + 7) / 8, 512, 0, stream>>>(gru_pk, hbuf16, h_prev,
                                                   b_ih, b_hh, W_ro, b_ro,
                                                   out_h, out_o);
}

// Round 10
// 250.093 us; speedup vs baseline: 1.2777x; 1.2777x over previous
//
#include <hip/hip_runtime.h>
#include <hip/hip_bf16.h>

#define N_NODES 100000
#define N_HEDGES 20000
#define N_EDGES 800000
#define HSEG (2 * N_HEDGES)            // 40000 hedge segments (t,h)
#define NSEG (2 * N_NODES)             // 200000 node segments (t,n)
#define MSEG (HSEG + NSEG)             // 240000 segments

// Two-level LDS bucket sort geometry:
#define EPB 4096                        // edges per pass-A/C block
#define NBLK_A ((N_EDGES + EPB - 1) / EPB)  // 196
#define NHB 313                         // hedge buckets: 128 segs each
#define NBUCK 704                       // + 391 node buckets: 512 segs each
#define TOTB (NBUCK * NBLK_A)           // 137,984 (bucket-major counts)
#define SCANB ((TOTB + 2047) / 2048)    // 68
#define RKCAP 8192                      // max entries/bucket (mean ~2.3K)

#define CAST_BLOCKS (N_NODES * 64 / 8 / 256)   // 3125
#define PACK_BLOCKS 16

#define MIX_PK  (4 * 4 * 64 * 8)        // 8192 packed bf16 fused-mix weights
#define GRU_PK  (2 * 2 * 12 * 64 * 8)   // 24576 for k_gru

typedef __hip_bfloat16 bf16;
typedef __attribute__((ext_vector_type(8))) short bf16x8;
typedef __attribute__((ext_vector_type(4))) float f32x4;

__device__ __forceinline__ bf16 f2b(float v) { return __float2bfloat16(v); }
__device__ __forceinline__ short f2s(float v) {
    bf16 b = __float2bfloat16(v);
    return *reinterpret_cast<short*>(&b);
}
__device__ __forceinline__ uint pk2(float a, float b) {
    return (uint)(unsigned short)f2s(a) | ((uint)(unsigned short)f2s(b) << 16);
}
__device__ __forceinline__ bf16x8 pack8(float4 a, float4 b) {
    bf16x8 r = {f2s(a.x), f2s(a.y), f2s(a.z), f2s(a.w),
                f2s(b.x), f2s(b.y), f2s(b.z), f2s(b.w)};
    return r;
}
__device__ __forceinline__ float fast_sigmoid(float x) {
    return __builtin_amdgcn_rcpf(1.f + __expf(-x));
}
__device__ __forceinline__ float fast_tanh(float x) {
    return 1.f - 2.f * __builtin_amdgcn_rcpf(1.f + __expf(2.f * x));
}

// ---------------------------------------------------------------------------
// FRONT kernel, three roles by blockIdx (unchanged — passed rounds 7-9).
// ---------------------------------------------------------------------------
__global__ __launch_bounds__(256) void k_front(
    const int* __restrict__ node_idx, const int* __restrict__ hedge_idx,
    const int* __restrict__ attr, uint* __restrict__ rk12,
    int* __restrict__ bcnt,
    const float* __restrict__ x, bf16* __restrict__ xb,
    const float* __restrict__ Wc, const float* __restrict__ Wm,
    const float* __restrict__ bc_g, const float* __restrict__ bm,
    const float* __restrict__ Wih, const float* __restrict__ Whh,
    bf16* __restrict__ gru_pk, bf16* __restrict__ mixf_pk,
    float* __restrict__ bfused) {
    __shared__ int bc[NBUCK];
    int b = blockIdx.x;
    int tid = threadIdx.x;
    if (b < NBLK_A) {
        for (int i = tid; i < NBUCK; i += 256) bc[i] = 0;
        __syncthreads();
        int e0 = b * EPB;
        for (int it = 0; it < EPB / 256; ++it) {
            int e = e0 + it * 256 + tid;
            if (e < N_EDGES) {
                int t = attr[e];
                int s1 = t * N_HEDGES + hedge_idx[e];
                int s2 = HSEG + t * N_NODES + node_idx[e];
                int b1 = s1 >> 7;
                int b2 = NHB + ((s2 - HSEG) >> 9);
                int r1 = atomicAdd(&bc[b1], 1);
                int r2 = atomicAdd(&bc[b2], 1);
                rk12[e] = (uint)(r1 & 0xFFFF) | ((uint)r2 << 16);
            }
        }
        __syncthreads();
        for (int i = tid; i < NBUCK; i += 256) bcnt[i * NBLK_A + b] = bc[i];
    } else if (b < NBLK_A + CAST_BLOCKS) {
        size_t i = ((size_t)(b - NBLK_A) * 256 + tid) * 8;
        const float* xp = x + i;
        float4 a = *(const float4*)xp;
        float4 bb = *(const float4*)(xp + 4);
        *(bf16x8*)(xb + i) = pack8(a, bb);
    } else {
        int idx = (b - NBLK_A - CAST_BLOCKS) * 256 + tid;
        int stride = PACK_BLOCKS * 256;
        for (int i = idx; i < GRU_PK; i += stride) {
            int j = i & 7;
            int r = i >> 3;
            int ln = r & 63;
            int r2i = r >> 6;
            int ct = r2i % 12;
            int r3 = r2i / 12;
            int kt = r3 & 1;
            int mat = r3 >> 1;
            int k = kt * 32 + ((ln >> 4) << 3) + j;
            int n = ct * 16 + (ln & 15);
            float v = mat == 0 ? Wih[k * 192 + n] : Whh[k * 192 + n];
            gru_pk[i] = f2b(v);
        }
        for (int i = idx; i < MIX_PK; i += stride) {
            int j = i & 7, ln = (i >> 3) & 63, r2i = i >> 9;
            int ct = r2i & 3, kt = r2i >> 2;
            int k = kt * 32 + ((ln >> 4) << 3) + j;   // 0..127 (concat dim)
            int n = ct * 16 + (ln & 15);
            int t = k >> 6, kk = k & 63;
            float s = 0.f;
            for (int q = 0; q < 64; ++q)
                s += Wc[((size_t)t * 64 + kk) * 64 + q] * Wm[(size_t)(t * 64 + q) * 64 + n];
            mixf_pk[i] = f2b(s);
        }
        for (int i = idx; i < 64; i += stride) {
            float s = bm[i];
            for (int q = 0; q < 64; ++q)
                s += bc_g[q] * Wm[(size_t)q * 64 + i] + bc_g[64 + q] * Wm[(size_t)(64 + q) * 64 + i];
            bfused[i] = s;
        }
    }
}

// ---------------------------------------------------------------------------
// Scan 1/3 over bcnt, IN-PLACE safe (block reads its range before writing).
// ---------------------------------------------------------------------------
__global__ __launch_bounds__(256) void k_scan1(const int* __restrict__ cnt,
                                               int* __restrict__ off,
                                               int* __restrict__ bsum) {
    __shared__ int s[256];
    int base = blockIdx.x * 2048 + threadIdx.x * 8;
    int v[8];
    int tsum = 0;
#pragma unroll
    for (int j = 0; j < 8; ++j) {
        int g = base + j;
        v[j] = (g < TOTB) ? cnt[g] : 0;
        tsum += v[j];
    }
    s[threadIdx.x] = tsum;
    __syncthreads();
    for (int o = 1; o < 256; o <<= 1) {
        int t = (threadIdx.x >= o) ? s[threadIdx.x - o] : 0;
        __syncthreads();
        s[threadIdx.x] += t;
        __syncthreads();
    }
    int run = s[threadIdx.x] - tsum;
#pragma unroll
    for (int j = 0; j < 8; ++j) {
        int g = base + j;
        if (g < TOTB) off[g] = run;
        run += v[j];
    }
    if (threadIdx.x == 255) bsum[blockIdx.x] = s[255];
}

__global__ __launch_bounds__(1024) void k_scan2(int* __restrict__ bsum) {
    __shared__ int s[1024];
    int tid = threadIdx.x;
    int v = (tid < SCANB) ? bsum[tid] : 0;
    s[tid] = v;
    __syncthreads();
    for (int o = 1; o < 1024; o <<= 1) {
        int t = (tid >= o) ? s[tid - o] : 0;
        __syncthreads();
        s[tid] += t;
        __syncthreads();
    }
    if (tid < SCANB) bsum[tid] = s[tid] - v;
}

__global__ __launch_bounds__(256) void k_scan3(int* __restrict__ off,
                                               const int* __restrict__ bsum) {
    int base = blockIdx.x * 2048 + threadIdx.x * 8;
    int add = bsum[blockIdx.x];
#pragma unroll
    for (int j = 0; j < 8; ++j) {
        int g = base + j;
        if (g < TOTB) off[g] += add;
    }
    if (blockIdx.x == 0 && threadIdx.x == 0) off[TOTB] = 2 * N_EDGES;  // sentinel
}

// ---------------------------------------------------------------------------
// Bucket-sort pass C: ATOMIC-FREE scatter into bucket-major pairs array.
// ---------------------------------------------------------------------------
__global__ __launch_bounds__(256) void k_bscatter(const int* __restrict__ node_idx,
                                                  const int* __restrict__ hedge_idx,
                                                  const int* __restrict__ attr,
                                                  const uint* __restrict__ rk12,
                                                  const int* __restrict__ bbase,
                                                  int2* __restrict__ pairs) {
    int b = blockIdx.x, tid = threadIdx.x;
    int e0 = b * EPB;
    for (int it = 0; it < EPB / 256; ++it) {
        int e = e0 + it * 256 + tid;
        if (e < N_EDGES) {
            int t = attr[e], n = node_idx[e], h = hedge_idx[e];
            int s1 = t * N_HEDGES + h;
            int s2 = HSEG + t * N_NODES + n;
            int b1 = s1 >> 7;
            int b2 = NHB + ((s2 - HSEG) >> 9);
            uint rk = rk12[e];
            int p1 = bbase[b1 * NBLK_A + b] + (int)(rk & 0xFFFF);
            int p2 = bbase[b2 * NBLK_A + b] + (int)(rk >> 16);
            pairs[p1] = make_int2(s1, n);
            pairs[p2] = make_int2(s2, t * N_HEDGES + h);
        }
    }
}

// ---------------------------------------------------------------------------
// Bucket-sort pass D: one block per bucket -> dense CSR off[] + sortedAll.
// ---------------------------------------------------------------------------
__global__ __launch_bounds__(256) void k_bfinal(const int* __restrict__ bbase,
                                                const int2* __restrict__ pairs,
                                                int* __restrict__ off,
                                                int* __restrict__ sortedAll) {
    __shared__ int scnt[512];
    __shared__ int exs[512];
    __shared__ int ssum[256];
    __shared__ unsigned short rk[RKCAP];
    int bucket = blockIdx.x, tid = threadIdx.x;
    int seg_first, nseg;
    if (bucket < NHB) {
        seg_first = bucket << 7;
        nseg = min(128, HSEG - seg_first);
    } else {
        int bi = bucket - NHB;
        seg_first = HSEG + (bi << 9);
        nseg = min(512, MSEG - seg_first);
    }
    int bstart = bbase[bucket * NBLK_A];
    int bend = bbase[(bucket + 1) * NBLK_A];   // sentinel covers last bucket
    for (int i = tid; i < 512; i += 256) scnt[i] = 0;
    __syncthreads();
    for (int i = bstart + tid; i < bend; i += 256) {
        int li = i - bstart;
        int key = pairs[i].x;
        int r = atomicAdd(&scnt[key - seg_first], 1);
        if (li < RKCAP) rk[li] = (unsigned short)r;
    }
    __syncthreads();
    int a0 = (2 * tid < nseg) ? scnt[2 * tid] : 0;
    int a1 = (2 * tid + 1 < nseg) ? scnt[2 * tid + 1] : 0;
    ssum[tid] = a0 + a1;
    __syncthreads();
    for (int o = 1; o < 256; o <<= 1) {
        int t = (tid >= o) ? ssum[tid - o] : 0;
        __syncthreads();
        ssum[tid] += t;
        __syncthreads();
    }
    int pb = ssum[tid] - (a0 + a1);
    exs[2 * tid] = pb;
    exs[2 * tid + 1] = pb + a0;
    if (2 * tid < nseg) off[seg_first + 2 * tid] = bstart + pb;
    if (2 * tid + 1 < nseg) off[seg_first + 2 * tid + 1] = bstart + pb + a0;
    if (bucket == NBUCK - 1 && tid == 0) off[MSEG] = 2 * N_EDGES;
    __syncthreads();
    for (int i = bstart + tid; i < bend; i += 256) {
        int li = i - bstart;
        if (li < RKCAP) {
            int2 pr = pairs[i];
            int pos = bstart + exs[pr.x - seg_first] + (int)rk[li];
            sortedAll[pos] = pr.y;
        }
    }
}

// ---------------------------------------------------------------------------
// One contiguous run: 2-deep pipelined gather (8-lane half-group, uint4).
// NO cross-lane combine here (caller shfl_xor(8)'s the final value).
// ---------------------------------------------------------------------------
__device__ __forceinline__ void run_gather(const int* __restrict__ sortedAll,
                                           const bf16* __restrict__ rows,
                                           int myb, int mye, int i0, int cb,
                                           float acc[8]) {
#pragma unroll
    for (int j = 0; j < 8; ++j) acc[j] = 0.f;
    int i = myb + i0;
    for (; i + 2 < mye; i += 4) {
        int idx0 = sortedAll[i];
        int idx1 = sortedAll[i + 2];
        uint4 v0 = *(const uint4*)(rows + (size_t)idx0 * 64 + cb);
        uint4 v1 = *(const uint4*)(rows + (size_t)idx1 * 64 + cb);
        acc[0] += __uint_as_float(v0.x << 16);
        acc[1] += __uint_as_float(v0.x & 0xffff0000u);
        acc[2] += __uint_as_float(v0.y << 16);
        acc[3] += __uint_as_float(v0.y & 0xffff0000u);
        acc[4] += __uint_as_float(v0.z << 16);
        acc[5] += __uint_as_float(v0.z & 0xffff0000u);
        acc[6] += __uint_as_float(v0.w << 16);
        acc[7] += __uint_as_float(v0.w & 0xffff0000u);
        acc[0] += __uint_as_float(v1.x << 16);
        acc[1] += __uint_as_float(v1.x & 0xffff0000u);
        acc[2] += __uint_as_float(v1.y << 16);
        acc[3] += __uint_as_float(v1.y & 0xffff0000u);
        acc[4] += __uint_as_float(v1.z << 16);
        acc[5] += __uint_as_float(v1.z & 0xffff0000u);
        acc[6] += __uint_as_float(v1.w << 16);
        acc[7] += __uint_as_float(v1.w & 0xffff0000u);
    }
    if (i < mye) {
        int idx = sortedAll[i];
        uint4 v = *(const uint4*)(rows + (size_t)idx * 64 + cb);
        acc[0] += __uint_as_float(v.x << 16);
        acc[1] += __uint_as_float(v.x & 0xffff0000u);
        acc[2] += __uint_as_float(v.y << 16);
        acc[3] += __uint_as_float(v.y & 0xffff0000u);
        acc[4] += __uint_as_float(v.z << 16);
        acc[5] += __uint_as_float(v.z & 0xffff0000u);
        acc[6] += __uint_as_float(v.w << 16);
        acc[7] += __uint_as_float(v.w & 0xffff0000u);
    }
}

// ---------------------------------------------------------------------------
// FUSED hedge gather + Wf GEMM: eg[t][h] = (Binv * sum xb rows) @ Wf_t.
// (unchanged from round 9)
// ---------------------------------------------------------------------------
__global__ __launch_bounds__(256) void k_ef2w(const int* __restrict__ off,
                                              const int* __restrict__ sortedAll,
                                              const bf16* __restrict__ xb,
                                              const bf16* __restrict__ mixf_pk,
                                              bf16* __restrict__ eg16) {
    __shared__ __align__(16) bf16 Wl[2 * 4 * 64 * 8];  // 8 KB: this-t Wf slice
    __shared__ __align__(16) bf16 tile[16 * 64];       // 2 KB
    int seg0b = blockIdx.x * 16;
    int t = (seg0b >= N_HEDGES) ? 1 : 0;
    {
        const bf16x8* src = (const bf16x8*)(mixf_pk + t * 4096);
        bf16x8* dst = (bf16x8*)Wl;
        for (int i = threadIdx.x; i < 4096 / 8; i += 256) dst[i] = src[i];
    }
    int wid = threadIdx.x >> 6, lane = threadIdx.x & 63;
    int q = lane >> 4, l16 = lane & 15;

    // gather this wave's 4 segments (rows wid*4+q of the tile)
    int seg0 = seg0b + wid * 4;
    int ov = 0;
    if (lane < 5) ov = off[seg0 + lane];
    int myb = __shfl(ov, q);
    int mye = __shfl(ov, q + 1);
    float acc[8];
    run_gather(sortedAll, xb, myb, mye, l16 >> 3, (l16 & 7) * 8, acc);
#pragma unroll
    for (int j = 0; j < 8; ++j) acc[j] += __shfl_xor(acc[j], 8);
    float scale = (mye > myb) ? 1.0f / (float)(mye - myb) : 0.f;
    int r = wid * 4 + q;
    if (l16 < 8) {
        int cs = l16 ^ (r & 7);                    // chunk-XOR swizzle
        uint4 w;
        w.x = pk2(acc[0] * scale, acc[1] * scale);
        w.y = pk2(acc[2] * scale, acc[3] * scale);
        w.z = pk2(acc[4] * scale, acc[5] * scale);
        w.w = pk2(acc[6] * scale, acc[7] * scale);
        *(uint4*)&tile[r * 64 + cs * 8] = w;
    }
    __syncthreads();

    bf16x8 a0 = *(const bf16x8*)&tile[l16 * 64 + (q ^ (l16 & 7)) * 8];
    bf16x8 a1 = *(const bf16x8*)&tile[l16 * 64 + ((q + 4) ^ (l16 & 7)) * 8];
    const f32x4 zero = {0.f, 0.f, 0.f, 0.f};
#define LDW(ktl) (*(const bf16x8*)&Wl[(((ktl)*4 + wid) * 64 + lane) * 8])
    f32x4 d = __builtin_amdgcn_mfma_f32_16x16x32_bf16(a0, LDW(0), zero, 0, 0, 0);
    d = __builtin_amdgcn_mfma_f32_16x16x32_bf16(a1, LDW(1), d, 0, 0, 0);
#undef LDW
#pragma unroll
    for (int rg = 0; rg < 4; ++rg)
        eg16[(size_t)(seg0b + q * 4 + rg) * 64 + wid * 16 + l16] = f2b(d[rg]);
}

// ---------------------------------------------------------------------------
// Node aggregation, BOTH types fused (unchanged from round 9): h[n] =
// relu(a0*Dinv0 + a1*Dinv1 + bfused) -> hbuf16.
// ---------------------------------------------------------------------------
__global__ __launch_bounds__(256) void k_no2h(const int* __restrict__ off,
                                              const int* __restrict__ sortedAll,
                                              const bf16* __restrict__ eg16,
                                              const float* __restrict__ bfused,
                                              bf16* __restrict__ hbuf16) {
    int wid = threadIdx.x >> 6, lane = threadIdx.x & 63;
    int n0 = (blockIdx.x * 4 + wid) * 4;
    if (n0 >= N_NODES) return;
    int q = lane >> 4, l16 = lane & 15;
    int cb = (l16 & 7) * 8, i0 = l16 >> 3;
    int ov = 0;
    if (lane < 5) ov = off[HSEG + n0 + lane];
    else if (lane >= 8 && lane < 13) ov = off[HSEG + N_NODES + n0 + (lane - 8)];
    int b0 = __shfl(ov, q), e0 = __shfl(ov, q + 1);
    int b1 = __shfl(ov, 8 + q), e1 = __shfl(ov, 9 + q);
    float a0[8], a1[8];
    run_gather(sortedAll, eg16, b0, e0, i0, cb, a0);
    run_gather(sortedAll, eg16, b1, e1, i0, cb, a1);
    float s0 = (e0 > b0) ? 1.0f / (float)(e0 - b0) : 0.f;
    float s1 = (e1 > b1) ? 1.0f / (float)(e1 - b1) : 0.f;
    float v[8];
#pragma unroll
    for (int j = 0; j < 8; ++j) {
        v[j] = a0[j] * s0 + a1[j] * s1;
        v[j] += __shfl_xor(v[j], 8);
    }
    if (l16 < 8) {
#pragma unroll
        for (int j = 0; j < 8; ++j) v[j] = fmaxf(v[j] + bfused[cb + j], 0.f);
        uint4 w;
        w.x = pk2(v[0], v[1]);
        w.y = pk2(v[2], v[3]);
        w.z = pk2(v[4], v[5]);
        w.w = pk2(v[6], v[7]);
        *(uint4*)(hbuf16 + (size_t)(n0 + q) * 64 + cb) = w;
    }
}

// ---------------------------------------------------------------------------
// PURE GRU — 256-THREAD blocks, plain __launch_bounds__(256): round-9's
// __launch_bounds__(512) capped VGPR at 128 (4 waves/SIMD target) and the
// ~150-reg body spilled 175MB to scratch (FETCH 115MB/WRITE 201MB, 102us).
// The 256-thread config is the empirically spill-free one (rounds 3-8).
// LDS 48KB -> 3 blocks/CU. Gate fusion r/z, biases in C-init, fast act.
// ---------------------------------------------------------------------------
#define GRU_TILES (N_NODES / 16)
__global__ __launch_bounds__(256) void k_gru(const bf16* __restrict__ gru_pk,
                                             const bf16* __restrict__ hbuf16,
                                             const float* __restrict__ h_prev,
                                             const float* __restrict__ bih_g,
                                             const float* __restrict__ bhh_g,
                                             const float* __restrict__ Wro_g,
                                             const float* __restrict__ bro_g,
                                             float* __restrict__ out_h,
                                             float* __restrict__ out_o) {
    __shared__ __align__(16) bf16 Wpk[GRU_PK];      // 48 KB
    {
        const bf16x8* src = (const bf16x8*)gru_pk;
        bf16x8* dst = (bf16x8*)Wpk;
        for (int i = threadIdx.x; i < GRU_PK / 8; i += 256) dst[i] = src[i];
    }
    __syncthreads();

    int wid = threadIdx.x >> 6, lane = threadIdx.x & 63;
    int quad = lane >> 4, l16 = lane & 15;

    float br_c[4], bz_c[4], bin_c[4], bhn_c[4], wv[4][3];
#pragma unroll
    for (int cc = 0; cc < 4; ++cc) {
        int col = cc * 16 + l16;
        br_c[cc] = bih_g[col] + bhh_g[col];
        bz_c[cc] = bih_g[64 + col] + bhh_g[64 + col];
        bin_c[cc] = bih_g[128 + col];
        bhn_c[cc] = bhh_g[128 + col];
        wv[cc][0] = Wro_g[col * 64 + 0];
        wv[cc][1] = Wro_g[col * 64 + 1];
        wv[cc][2] = Wro_g[col * 64 + 2];
    }
    float bro0 = bro_g[0], bro1 = bro_g[1], bro2 = bro_g[2];

    int wave = blockIdx.x * 4 + wid;
    int n_waves = gridDim.x * 4;

    for (int tile = wave; tile < GRU_TILES; tile += n_waves) {
        int row0 = tile * 16;
        int arow = row0 + l16;
        const bf16* ha_p = hbuf16 + (size_t)arow * 64 + quad * 8;
        bf16x8 ha0 = *(const bf16x8*)ha_p;
        bf16x8 ha1 = *(const bf16x8*)(ha_p + 32);
        const float* pp = h_prev + (size_t)arow * 64 + quad * 8;
        bf16x8 pa0 = pack8(*(const float4*)pp, *(const float4*)(pp + 4));
        bf16x8 pa1 = pack8(*(const float4*)(pp + 32), *(const float4*)(pp + 36));

        float p[4][3];
#pragma unroll
        for (int rg = 0; rg < 4; ++rg) p[rg][0] = p[rg][1] = p[rg][2] = 0.f;

#pragma unroll
        for (int cc = 0; cc < 4; ++cc) {
#define LDB(mat, kt, ct) (*(const bf16x8*)&Wpk[((((mat)*2 + (kt)) * 12 + (ct)) * 64 + lane) * 8])
            f32x4 rs = {br_c[cc], br_c[cc], br_c[cc], br_c[cc]};
            f32x4 zs = {bz_c[cc], bz_c[cc], bz_c[cc], bz_c[cc]};
            f32x4 gin = {bin_c[cc], bin_c[cc], bin_c[cc], bin_c[cc]};
            f32x4 ghn = {bhn_c[cc], bhn_c[cc], bhn_c[cc], bhn_c[cc]};
            rs = __builtin_amdgcn_mfma_f32_16x16x32_bf16(ha0, LDB(0, 0, cc), rs, 0, 0, 0);
            rs = __builtin_amdgcn_mfma_f32_16x16x32_bf16(ha1, LDB(0, 1, cc), rs, 0, 0, 0);
            rs = __builtin_amdgcn_mfma_f32_16x16x32_bf16(pa0, LDB(1, 0, cc), rs, 0, 0, 0);
            rs = __builtin_amdgcn_mfma_f32_16x16x32_bf16(pa1, LDB(1, 1, cc), rs, 0, 0, 0);
            zs = __builtin_amdgcn_mfma_f32_16x16x32_bf16(ha0, LDB(0, 0, cc + 4), zs, 0, 0, 0);
            zs = __builtin_amdgcn_mfma_f32_16x16x32_bf16(ha1, LDB(0, 1, cc + 4), zs, 0, 0, 0);
            zs = __builtin_amdgcn_mfma_f32_16x16x32_bf16(pa0, LDB(1, 0, cc + 4), zs, 0, 0, 0);
            zs = __builtin_amdgcn_mfma_f32_16x16x32_bf16(pa1, LDB(1, 1, cc + 4), zs, 0, 0, 0);
            gin = __builtin_amdgcn_mfma_f32_16x16x32_bf16(ha0, LDB(0, 0, cc + 8), gin, 0, 0, 0);
            gin = __builtin_amdgcn_mfma_f32_16x16x32_bf16(ha1, LDB(0, 1, cc + 8), gin, 0, 0, 0);
            ghn = __builtin_amdgcn_mfma_f32_16x16x32_bf16(pa0, LDB(1, 0, cc + 8), ghn, 0, 0, 0);
            ghn = __builtin_amdgcn_mfma_f32_16x16x32_bf16(pa1, LDB(1, 1, cc + 8), ghn, 0, 0, 0);
#undef LDB
#pragma unroll
            for (int rg = 0; rg < 4; ++rg) {
                int row = row0 + quad * 4 + rg;
                float pv = h_prev[(size_t)row * 64 + cc * 16 + l16];
                float rr = fast_sigmoid(rs[rg]);
                float zz = fast_sigmoid(zs[rg]);
                float nn = fast_tanh(gin[rg] + rr * ghn[rg]);
                float hn = (1.f - zz) * nn + zz * pv;
                out_h[(size_t)row * 64 + cc * 16 + l16] = hn;
                p[rg][0] += hn * wv[cc][0];
                p[rg][1] += hn * wv[cc][1];
                p[rg][2] += hn * wv[cc][2];
            }
        }
#pragma unroll
        for (int rg = 0; rg < 4; ++rg) {
#pragma unroll
            for (int m = 1; m < 16; m <<= 1) {
                p[rg][0] += __shfl_xor(p[rg][0], m);
                p[rg][1] += __shfl_xor(p[rg][1], m);
                p[rg][2] += __shfl_xor(p[rg][2], m);
            }
        }
        if (l16 == 0) {
#pragma unroll
            for (int rg = 0; rg < 4; ++rg) {
                int row = row0 + quad * 4 + rg;
                out_o[(size_t)row * 3 + 0] = p[rg][0] + bro0;
                out_o[(size_t)row * 3 + 1] = p[rg][1] + bro1;
                out_o[(size_t)row * 3 + 2] = p[rg][2] + bro2;
            }
        }
    }
}

extern "C" void kernel_launch(void* const* d_in, const int* in_sizes, int n_in,
                              void* d_out, int out_size, void* d_ws, size_t ws_size,
                              hipStream_t stream) {
    const float* x        = (const float*)d_in[0];
    const float* h_prev   = (const float*)d_in[1];
    const int* node_idx   = (const int*)d_in[2];
    const int* hedge_idx  = (const int*)d_in[3];
    const int* edge_attr  = (const int*)d_in[4];
    const float* W_conv   = (const float*)d_in[5];
    const float* b_conv   = (const float*)d_in[6];
    const float* W_mix    = (const float*)d_in[7];
    const float* b_mix    = (const float*)d_in[8];
    const float* W_ih     = (const float*)d_in[9];
    const float* W_hh     = (const float*)d_in[10];
    const float* b_ih     = (const float*)d_in[11];
    const float* b_hh     = (const float*)d_in[12];
    const float* W_ro     = (const float*)d_in[13];
    const float* b_ro     = (const float*)d_in[14];

    char* p = (char*)d_ws;
    auto alloc = [&](size_t bytes) {
        char* r = p;
        p += (bytes + 63) & ~(size_t)63;
        return r;
    };
    // Region A (25.6MB): bucket-sort scratch {pairs 12.8MB, rk12 3.2MB,
    // bcnt 0.55MB, bsum 4KB} — all dead after k_bfinal — overlaid by
    // hbuf16 (12.8MB, first written in k_no2h).
    char* regA     = alloc((size_t)2 * N_NODES * 64 * 2);   // 25.6 MB
    int2* pairs    = (int2*)regA;
    uint* rk12     = (uint*)(pairs + 2 * N_EDGES);
    int* bcnt      = (int*)(rk12 + N_EDGES);
    int* bsum      = bcnt + TOTB + 1;
    bf16* hbuf16   = (bf16*)regA;
    int* off       = (int*)alloc((size_t)(MSEG + 1) * 4);   // live CSR ptrs
    int* sortedAll = (int*)alloc((size_t)2 * N_EDGES * 4);
    bf16* xb       = (bf16*)alloc((size_t)N_NODES * 64 * 2);
    bf16* eg16     = (bf16*)alloc((size_t)HSEG * 64 * 2);
    bf16* gru_pk   = (bf16*)alloc((size_t)GRU_PK * 2);
    bf16* mixf_pk  = (bf16*)alloc((size_t)MIX_PK * 2);
    float* bfused  = (float*)alloc(64 * 4);

    float* out_h = (float*)d_out;
    float* out_o = out_h + (size_t)N_NODES * 64;

    k_front<<<NBLK_A + CAST_BLOCKS + PACK_BLOCKS, 256, 0, stream>>>(
        node_idx, hedge_idx, edge_attr, rk12, bcnt, x, xb,
        W_conv, W_mix, b_conv, b_mix, W_ih, W_hh, gru_pk, mixf_pk, bfused);
    k_scan1<<<SCANB, 256, 0, stream>>>(bcnt, bcnt, bsum);   // in-place
    k_scan2<<<1, 1024, 0, stream>>>(bsum);
    k_scan3<<<SCANB, 256, 0, stream>>>(bcnt, bsum);
    k_bscatter<<<NBLK_A, 256, 0, stream>>>(node_idx, hedge_idx, edge_attr,
                                           rk12, bcnt, pairs);
    k_bfinal<<<NBUCK, 256, 0, stream>>>(bcnt, pairs, off, sortedAll);
    k_ef2w<<<HSEG / 16, 256, 0, stream>>>(off, sortedAll, xb, mixf_pk, eg16);
    k_no2h<<<N_NODES / 16, 256, 0, stream>>>(off, sortedAll, eg16, bfused, hbuf16);
    k_gru<<<768, 256, 0, stream>>>(gru_pk, hbuf16, h_prev,
                                   b_ih, b_hh, W_ro, b_ro, out_h, out_o);
}